// Round 1
// baseline (1681.559 us; speedup 1.0000x reference)
//
#include <hip/hip_runtime.h>

#define KC 512
#define DD 64
#define NR 65536

// d_out layout (floats), reference return order:
// quantize_st[4194304], diff[1], embed_ind[65536], embed_new[32768],
// new_cluster_size[512], new_embed_avg[32768]
#define OFF_Q     0
#define OFF_DIFF  4194304
#define OFF_IND   4194305
#define OFF_ENEW  4259841
#define OFF_NCS   4292609
#define OFF_NAVG  4293121

// ws layout (floats)
#define WS_ET    0        // 32768: embed transposed [K][D]
#define WS_C     32768    // 512:   0.5*||e_k||^2
#define WS_CNT   33280    // 512:   one-hot counts
#define WS_ESUM  33792    // 32768: embed_sum transposed [K][D]
#define WS_DIFF  66560    // 1:     sum of squared diff
#define WS_NTOT  66561    // 1:     sum of new_cluster_size

// Prep: transpose embed [D][K] -> Et [K][D], code-norm bias, zero accumulators.
__global__ __launch_bounds__(256) void k_prep(const float* __restrict__ embed,
                                              float* __restrict__ ws) {
    int i = blockIdx.x * 256 + threadIdx.x;
    if (i < 512 + 32768 + 2) ws[WS_CNT + i] = 0.0f;   // counts, esum, diff, ntot
    if (i < 32768) {
        int k = i >> 6, d = i & 63;
        ws[WS_ET + i] = embed[d * KC + k];
    }
    if (i < 512) {
        float s = 0.0f;
        #pragma unroll
        for (int d = 0; d < 64; ++d) { float e = embed[d * KC + i]; s = fmaf(e, e, s); }
        ws[WS_C + i] = 0.5f * s;
    }
}

// Main: per-row argmax_k (x . e_k - 0.5||e_k||^2), quantize gather, diff,
// and fused EMA scatter (counts + embed_sum) via global atomics.
__global__ __launch_bounds__(256) void k_dist(const float* __restrict__ input,
                                              const float* __restrict__ Et,
                                              const float* __restrict__ c,
                                              float* __restrict__ out,
                                              float* __restrict__ counts,
                                              float* __restrict__ esum,
                                              float* __restrict__ diffsum) {
    int n = blockIdx.x * 256 + threadIdx.x;
    float x[64];
    const float4* xr = reinterpret_cast<const float4*>(input + (size_t)n * 64);
    #pragma unroll
    for (int i = 0; i < 16; ++i) {
        float4 v = xr[i];
        x[4*i+0] = v.x; x[4*i+1] = v.y; x[4*i+2] = v.z; x[4*i+3] = v.w;
    }

    float best = -3.0e38f; int bk = 0;
    // Et/c accesses are wave-uniform -> compiler emits scalar (s_load) reads,
    // keeping the VALU free for the 4 independent FMA chains.
    for (int k = 0; k < KC; k += 4) {
        float s0 = -c[k+0], s1 = -c[k+1], s2 = -c[k+2], s3 = -c[k+3];
        #pragma unroll
        for (int d = 0; d < 64; ++d) {
            float xd = x[d];
            s0 = fmaf(xd, Et[(k+0)*64 + d], s0);
            s1 = fmaf(xd, Et[(k+1)*64 + d], s1);
            s2 = fmaf(xd, Et[(k+2)*64 + d], s2);
            s3 = fmaf(xd, Et[(k+3)*64 + d], s3);
        }
        if (s0 > best) { best = s0; bk = k;   }
        if (s1 > best) { best = s1; bk = k+1; }
        if (s2 > best) { best = s2; bk = k+2; }
        if (s3 > best) { best = s3; bk = k+3; }
    }

    // quantize gather + squared-diff
    const float4* e4 = reinterpret_cast<const float4*>(Et + (size_t)bk * 64);
    float4* q4 = reinterpret_cast<float4*>(out + OFF_Q + (size_t)n * 64);
    float dsum = 0.0f;
    #pragma unroll
    for (int i = 0; i < 16; ++i) {
        float4 v = e4[i];
        q4[i] = v;
        float d0 = v.x - x[4*i+0], d1 = v.y - x[4*i+1];
        float d2 = v.z - x[4*i+2], d3 = v.w - x[4*i+3];
        dsum += d0*d0 + d1*d1 + d2*d2 + d3*d3;
    }
    out[OFF_IND + n] = (float)bk;

    #pragma unroll
    for (int off = 32; off > 0; off >>= 1) dsum += __shfl_down(dsum, off);
    if ((threadIdx.x & 63) == 0) atomicAdd(diffsum, dsum);

    atomicAdd(&counts[bk], 1.0f);
    #pragma unroll
    for (int d = 0; d < 64; ++d) atomicAdd(&esum[bk * 64 + d], x[d]);
}

// new_cluster_size + its sum + diff finalize (single block).
__global__ __launch_bounds__(512) void k_ncs(const float* __restrict__ cluster_size,
                                             const float* __restrict__ ws,
                                             float* __restrict__ out,
                                             float* __restrict__ wsw) {
    __shared__ float red[512];
    int t = threadIdx.x;
    float ncs = cluster_size[t] * 0.99f + (1.0f - 0.99f) * ws[WS_CNT + t];
    out[OFF_NCS + t] = ncs;
    red[t] = ncs;
    __syncthreads();
    for (int off = 256; off > 0; off >>= 1) {
        if (t < off) red[t] += red[t + off];
        __syncthreads();
    }
    if (t == 0) {
        wsw[WS_NTOT] = red[0];
        out[OFF_DIFF] = ws[WS_DIFF] * (1.0f / 4194304.0f);
    }
}

// new_embed_avg + embed_new.
__global__ __launch_bounds__(512) void k_emb(const float* __restrict__ embed_avg,
                                             const float* __restrict__ ws,
                                             float* __restrict__ out) {
    int d = blockIdx.x;
    int t = threadIdx.x;
    float ncs = out[OFF_NCS + t];
    float ntot = ws[WS_NTOT];
    float csk = (ncs + 1e-5f) / (ntot + 512.0f * 1e-5f) * ntot;
    int idx = d * KC + t;
    float avg = embed_avg[idx] * 0.99f + (1.0f - 0.99f) * ws[WS_ESUM + t * 64 + d];
    out[OFF_NAVG + idx] = avg;
    out[OFF_ENEW + idx] = avg / csk;
}

extern "C" void kernel_launch(void* const* d_in, const int* in_sizes, int n_in,
                              void* d_out, int out_size, void* d_ws, size_t ws_size,
                              hipStream_t stream) {
    const float* input        = (const float*)d_in[0];
    const float* embed        = (const float*)d_in[1];
    const float* cluster_size = (const float*)d_in[2];
    const float* embed_avg    = (const float*)d_in[3];
    float* out = (float*)d_out;
    float* ws  = (float*)d_ws;

    k_prep<<<131, 256, 0, stream>>>(embed, ws);
    k_dist<<<256, 256, 0, stream>>>(input, ws + WS_ET, ws + WS_C, out,
                                    ws + WS_CNT, ws + WS_ESUM, ws + WS_DIFF);
    k_ncs<<<1, 512, 0, stream>>>(cluster_size, ws, out, ws);
    k_emb<<<64, 512, 0, stream>>>(embed_avg, ws, out);
}

// Round 2
// 370.303 us; speedup vs baseline: 4.5410x; 4.5410x over previous
//
#include <hip/hip_runtime.h>

#define KC 512
#define DD 64
#define NR 65536

// d_out layout (floats), reference return order:
// quantize_st[4194304], diff[1], embed_ind[65536], embed_new[32768],
// new_cluster_size[512], new_embed_avg[32768]
#define OFF_Q     0
#define OFF_DIFF  4194304
#define OFF_IND   4194305
#define OFF_ENEW  4259841
#define OFF_NCS   4292609
#define OFF_NAVG  4293121

// ws layout (floats)
#define WS_ET    0        // 32768: embed transposed [K][D]
#define WS_C     32768    // 512:   0.5*||e_k||^2
#define WS_CNT   33280    // 512:   one-hot counts
#define WS_ESUM  33792    // 32768: embed_sum transposed [K][D]
#define WS_DIFF  66560    // 1:     sum of squared diff
#define WS_NTOT  66561    // 1:     sum of new_cluster_size

// Prep: transpose embed [D][K] -> Et [K][D], code-norm bias, zero accumulators.
__global__ __launch_bounds__(256) void k_prep(const float* __restrict__ embed,
                                              float* __restrict__ ws) {
    int i = blockIdx.x * 256 + threadIdx.x;
    if (i < 512 + 32768 + 2) ws[WS_CNT + i] = 0.0f;   // counts, esum, diff, ntot
    if (i < 32768) {
        int k = i >> 6, d = i & 63;
        ws[WS_ET + i] = embed[d * KC + k];
    }
    if (i < 512) {
        float s = 0.0f;
        #pragma unroll
        for (int d = 0; d < 64; ++d) { float e = embed[d * KC + i]; s = fmaf(e, e, s); }
        ws[WS_C + i] = 0.5f * s;
    }
}

// Fused main: 1024 threads/block = 256 rows x 4 K-chunks (128 codes each).
// Phase 1: per-chunk argmax of (x.e - 0.5||e||^2). Phase 2: LDS reduce -> bk.
// Phase 3: gather/quantize/diff (all 1024 threads). Phase 4: coalesced scatter.
__global__ __launch_bounds__(1024) void k_main(const float* __restrict__ input,
                                               const float* __restrict__ Et,
                                               const float* __restrict__ c,
                                               float* __restrict__ out,
                                               float* __restrict__ counts,
                                               float* __restrict__ esum,
                                               float* __restrict__ diffsum) {
    __shared__ float sbest[4][256];
    __shared__ int   sidx[4][256];
    __shared__ int   fbk[256];
    __shared__ float wred[16];

    const int t     = threadIdx.x;
    const int r     = t & 255;        // local row
    const int chunk = t >> 8;         // k-chunk 0..3
    const int base  = blockIdx.x * 256;
    const int row   = base + r;

    // load x row into 16 float4 registers (static indices only)
    float4 X[16];
    const float4* x4 = reinterpret_cast<const float4*>(input) + (size_t)row * 16;
    #pragma unroll
    for (int i = 0; i < 16; ++i) X[i] = x4[i];

    const float4* E4 = reinterpret_cast<const float4*>(Et);
    const int kbase = chunk * 128;

    float best = -3.0e38f; int bk = kbase;
    for (int k = kbase; k < kbase + 128; k += 4) {
        float s0 = -c[k+0], s1 = -c[k+1], s2 = -c[k+2], s3 = -c[k+3];
        #pragma unroll
        for (int i = 0; i < 16; ++i) {
            float4 xv = X[i];
            float4 a0 = E4[(k+0)*16 + i];
            float4 a1 = E4[(k+1)*16 + i];
            float4 a2 = E4[(k+2)*16 + i];
            float4 a3 = E4[(k+3)*16 + i];
            s0 = fmaf(xv.x, a0.x, s0); s0 = fmaf(xv.y, a0.y, s0);
            s0 = fmaf(xv.z, a0.z, s0); s0 = fmaf(xv.w, a0.w, s0);
            s1 = fmaf(xv.x, a1.x, s1); s1 = fmaf(xv.y, a1.y, s1);
            s1 = fmaf(xv.z, a1.z, s1); s1 = fmaf(xv.w, a1.w, s1);
            s2 = fmaf(xv.x, a2.x, s2); s2 = fmaf(xv.y, a2.y, s2);
            s2 = fmaf(xv.z, a2.z, s2); s2 = fmaf(xv.w, a2.w, s2);
            s3 = fmaf(xv.x, a3.x, s3); s3 = fmaf(xv.y, a3.y, s3);
            s3 = fmaf(xv.z, a3.z, s3); s3 = fmaf(xv.w, a3.w, s3);
        }
        if (s0 > best) { best = s0; bk = k;   }
        if (s1 > best) { best = s1; bk = k+1; }
        if (s2 > best) { best = s2; bk = k+2; }
        if (s3 > best) { best = s3; bk = k+3; }
    }
    sbest[chunk][r] = best;
    sidx[chunk][r]  = bk;
    __syncthreads();

    // Phase 2: reduce 4 chunks (ascending chunk, strict > -> lowest k on ties)
    if (chunk == 0) {
        float b = sbest[0][r]; int k = sidx[0][r];
        #pragma unroll
        for (int cc = 1; cc < 4; ++cc) {
            float v = sbest[cc][r]; int kk = sidx[cc][r];
            if (v > b) { b = v; k = kk; }
        }
        fbk[r] = k;
        out[OFF_IND + row] = (float)k;
        atomicAdd(&counts[k], 1.0f);
    }
    __syncthreads();

    // Phase 3: gather + quantize + diff. thread t -> row t>>2, 16-float slice t&3.
    {
        int gr = t >> 2, p = t & 3;
        int k = fbk[gr];
        const float4* e4 = E4 + (size_t)k * 16 + p * 4;
        const float4* xs = reinterpret_cast<const float4*>(input) + (size_t)(base + gr) * 16 + p * 4;
        float4* q4 = reinterpret_cast<float4*>(out + OFF_Q) + (size_t)(base + gr) * 16 + p * 4;
        float dsum = 0.0f;
        #pragma unroll
        for (int j = 0; j < 4; ++j) {
            float4 e = e4[j], xv = xs[j];
            q4[j] = e;
            float d0 = e.x - xv.x, d1 = e.y - xv.y, d2 = e.z - xv.z, d3 = e.w - xv.w;
            dsum += d0*d0 + d1*d1 + d2*d2 + d3*d3;
        }
        #pragma unroll
        for (int off = 32; off > 0; off >>= 1) dsum += __shfl_down(dsum, off);
        if ((t & 63) == 0) wred[t >> 6] = dsum;
    }
    __syncthreads();
    if (t == 0) {
        float s = 0.0f;
        #pragma unroll
        for (int w = 0; w < 16; ++w) s += wred[w];
        atomicAdd(diffsum, s);
    }

    // Phase 4: coalesced scatter. wave w handles local rows [w*16, w*16+16);
    // all 64 lanes add one element of the row -> lane-contiguous atomics.
    {
        int wid = t >> 6, lane = t & 63;
        #pragma unroll
        for (int j = 0; j < 16; ++j) {
            int lr = wid * 16 + j;
            int k = fbk[lr];
            float xv = input[(size_t)(base + lr) * 64 + lane];
            atomicAdd(&esum[k * 64 + lane], xv);
        }
    }
}

// new_cluster_size + its sum + diff finalize (single block).
__global__ __launch_bounds__(512) void k_ncs(const float* __restrict__ cluster_size,
                                             const float* __restrict__ ws,
                                             float* __restrict__ out,
                                             float* __restrict__ wsw) {
    __shared__ float red[512];
    int t = threadIdx.x;
    float ncs = cluster_size[t] * 0.99f + (1.0f - 0.99f) * ws[WS_CNT + t];
    out[OFF_NCS + t] = ncs;
    red[t] = ncs;
    __syncthreads();
    for (int off = 256; off > 0; off >>= 1) {
        if (t < off) red[t] += red[t + off];
        __syncthreads();
    }
    if (t == 0) {
        wsw[WS_NTOT] = red[0];
        out[OFF_DIFF] = ws[WS_DIFF] * (1.0f / 4194304.0f);
    }
}

// new_embed_avg + embed_new.
__global__ __launch_bounds__(512) void k_emb(const float* __restrict__ embed_avg,
                                             const float* __restrict__ ws,
                                             float* __restrict__ out) {
    int d = blockIdx.x;
    int t = threadIdx.x;
    float ncs = out[OFF_NCS + t];
    float ntot = ws[WS_NTOT];
    float csk = (ncs + 1e-5f) / (ntot + 512.0f * 1e-5f) * ntot;
    int idx = d * KC + t;
    float avg = embed_avg[idx] * 0.99f + (1.0f - 0.99f) * ws[WS_ESUM + t * 64 + d];
    out[OFF_NAVG + idx] = avg;
    out[OFF_ENEW + idx] = avg / csk;
}

extern "C" void kernel_launch(void* const* d_in, const int* in_sizes, int n_in,
                              void* d_out, int out_size, void* d_ws, size_t ws_size,
                              hipStream_t stream) {
    const float* input        = (const float*)d_in[0];
    const float* embed        = (const float*)d_in[1];
    const float* cluster_size = (const float*)d_in[2];
    const float* embed_avg    = (const float*)d_in[3];
    float* out = (float*)d_out;
    float* ws  = (float*)d_ws;

    k_prep<<<131, 256, 0, stream>>>(embed, ws);
    k_main<<<256, 1024, 0, stream>>>(input, ws + WS_ET, ws + WS_C, out,
                                     ws + WS_CNT, ws + WS_ESUM, ws + WS_DIFF);
    k_ncs<<<1, 512, 0, stream>>>(cluster_size, ws, out, ws);
    k_emb<<<64, 512, 0, stream>>>(embed_avg, ws, out);
}

// Round 3
// 166.929 us; speedup vs baseline: 10.0735x; 2.2183x over previous
//
#include <hip/hip_runtime.h>

#define KC 512
#define NR 65536

// d_out layout (floats), reference return order:
// quantize_st[4194304], diff[1], embed_ind[65536], embed_new[32768],
// new_cluster_size[512], new_embed_avg[32768]
#define OFF_Q     0
#define OFF_DIFF  4194304
#define OFF_IND   4194305
#define OFF_ENEW  4259841
#define OFF_NCS   4292609
#define OFF_NAVG  4293121

// ws layout (floats)
#define WS_ET    0        // 32768: embed transposed [K][D] (for gather)
#define WS_C     32768    // 512:   0.5*||e_k||^2
#define WS_CNT   33280    // 512:   one-hot counts
#define WS_ESUM  33792    // 32768: embed_sum transposed [K][D]
#define WS_DIFF  66560    // 1:     sum of squared diff
#define WS_NTOT  66561    // 1:     sum of new_cluster_size

__device__ __forceinline__ void fma4(float4& a, float s, const float4 e) {
    a.x = fmaf(s, e.x, a.x); a.y = fmaf(s, e.y, a.y);
    a.z = fmaf(s, e.z, a.z); a.w = fmaf(s, e.w, a.w);
}

// Prep: transpose embed [D][K] -> Et [K][D], code-norm bias, zero accumulators.
__global__ __launch_bounds__(256) void k_prep(const float* __restrict__ embed,
                                              float* __restrict__ ws) {
    int i = blockIdx.x * 256 + threadIdx.x;
    if (i < 512 + 32768 + 2) ws[WS_CNT + i] = 0.0f;   // counts, esum, diff, ntot
    if (i < 32768) {
        int k = i >> 6, d = i & 63;
        ws[WS_ET + i] = embed[d * KC + k];
    }
    if (i < 512) {
        float s = 0.0f;
        #pragma unroll
        for (int d = 0; d < 64; ++d) { float e = embed[d * KC + i]; s = fmaf(e, e, s); }
        ws[WS_C + i] = 0.5f * s;
    }
}

// Register-tiled main kernel. Block = 256 threads = 32 rows x 512 codes.
// Thread (tr=t>>5, tc=t&31): rows tr*4..tr*4+3, codes {128j + 4tc + jj}.
// acc[4][4] : 4 rows x 4 float4 code-groups = 64 scores per thread.
__global__ __launch_bounds__(256, 3) void k_main(const float* __restrict__ input,
                                                 const float* __restrict__ embed, // [64][512]
                                                 const float* __restrict__ Et,    // [512][64]
                                                 const float* __restrict__ c,
                                                 float* __restrict__ out,
                                                 float* __restrict__ counts,
                                                 float* __restrict__ esum,
                                                 float* __restrict__ diffsum) {
    __shared__ float Xt[64 * 32];   // X^T [d][r], 8 KB
    __shared__ int   fbk[32];
    __shared__ float sred[2];       // [0] = sum x^2, [1] = sum best

    const int t  = threadIdx.x;
    const int tc = t & 31;
    const int tr = t >> 5;
    const int base = blockIdx.x * 32;

    if (t < 2) sred[t] = 0.0f;

    // Stage X^T into LDS (coalesced global read), accumulate sum of x^2.
    float xs;
    {
        int r = t >> 3, dg = t & 7;
        const float4* xp = reinterpret_cast<const float4*>(input) + (size_t)(base + r) * 16 + dg * 2;
        float4 a = xp[0], b = xp[1];
        xs = a.x*a.x + a.y*a.y + a.z*a.z + a.w*a.w
           + b.x*b.x + b.y*b.y + b.z*b.z + b.w*b.w;
        int d0 = dg * 8;
        Xt[(d0+0)*32 + r] = a.x; Xt[(d0+1)*32 + r] = a.y;
        Xt[(d0+2)*32 + r] = a.z; Xt[(d0+3)*32 + r] = a.w;
        Xt[(d0+4)*32 + r] = b.x; Xt[(d0+5)*32 + r] = b.y;
        Xt[(d0+6)*32 + r] = b.z; Xt[(d0+7)*32 + r] = b.w;
        #pragma unroll
        for (int off = 32; off > 0; off >>= 1) xs += __shfl_down(xs, off);
    }
    __syncthreads();
    if ((t & 63) == 0) atomicAdd(&sred[0], xs);

    // acc init = -0.5*||e_k||^2
    float4 acc[4][4];
    {
        const float4* c4p = reinterpret_cast<const float4*>(c);
        #pragma unroll
        for (int j = 0; j < 4; ++j) {
            float4 cv = c4p[j * 32 + tc];
            cv.x = -cv.x; cv.y = -cv.y; cv.z = -cv.z; cv.w = -cv.w;
            acc[0][j] = cv; acc[1][j] = cv; acc[2][j] = cv; acc[3][j] = cv;
        }
    }

    const float4* E4  = reinterpret_cast<const float4*>(embed);
    const float4* XT4 = reinterpret_cast<const float4*>(Xt);

    // Main GEMM loop: per d, 1 LDS b128 (broadcast) + 4 coalesced global b128 + 64 FMA.
    #pragma unroll 2
    for (int d = 0; d < 64; ++d) {
        float4 xv = XT4[d * 8 + tr];
        float4 e0 = E4[d * 128 +  0 + tc];
        float4 e1 = E4[d * 128 + 32 + tc];
        float4 e2 = E4[d * 128 + 64 + tc];
        float4 e3 = E4[d * 128 + 96 + tc];
        fma4(acc[0][0], xv.x, e0); fma4(acc[1][0], xv.y, e0);
        fma4(acc[2][0], xv.z, e0); fma4(acc[3][0], xv.w, e0);
        fma4(acc[0][1], xv.x, e1); fma4(acc[1][1], xv.y, e1);
        fma4(acc[2][1], xv.z, e1); fma4(acc[3][1], xv.w, e1);
        fma4(acc[0][2], xv.x, e2); fma4(acc[1][2], xv.y, e2);
        fma4(acc[2][2], xv.z, e2); fma4(acc[3][2], xv.w, e2);
        fma4(acc[0][3], xv.x, e3); fma4(acc[1][3], xv.y, e3);
        fma4(acc[2][3], xv.z, e3); fma4(acc[3][3], xv.w, e3);
    }

    // Thread-local argmax (ascending k within thread; strict > = lowest-k tie).
    float bestv[4]; int bestk[4];
    #pragma unroll
    for (int m = 0; m < 4; ++m) {
        float b = -3.0e38f; int bk = 0;
        #pragma unroll
        for (int j = 0; j < 4; ++j) {
            int k0 = j * 128 + tc * 4;
            float4 v = acc[m][j];
            if (v.x > b) { b = v.x; bk = k0 + 0; }
            if (v.y > b) { b = v.y; bk = k0 + 1; }
            if (v.z > b) { b = v.z; bk = k0 + 2; }
            if (v.w > b) { b = v.w; bk = k0 + 3; }
        }
        bestv[m] = b; bestk[m] = bk;
    }

    // Cross-lane argmax over the 32 tc lanes (xor stays within 32-lane group).
    #pragma unroll
    for (int off = 1; off < 32; off <<= 1) {
        #pragma unroll
        for (int m = 0; m < 4; ++m) {
            float vv = __shfl_xor(bestv[m], off);
            int   kk = __shfl_xor(bestk[m], off);
            if (vv > bestv[m] || (vv == bestv[m] && kk < bestk[m])) {
                bestv[m] = vv; bestk[m] = kk;
            }
        }
    }

    if (tc == 0) {
        float bsum = bestv[0] + bestv[1] + bestv[2] + bestv[3];
        #pragma unroll
        for (int m = 0; m < 4; ++m) {
            int r = tr * 4 + m;
            fbk[r] = bestk[m];
            out[OFF_IND + base + r] = (float)bestk[m];
            atomicAdd(&counts[bestk[m]], 1.0f);
        }
        atomicAdd(&sred[1], bsum);
    }
    __syncthreads();

    // Quantize gather from Et [K][D].
    {
        int r = t >> 3, sl = t & 7;
        int k = fbk[r];
        const float4* ep = reinterpret_cast<const float4*>(Et) + (size_t)k * 16 + sl * 2;
        float4* qp = reinterpret_cast<float4*>(out + OFF_Q) + (size_t)(base + r) * 16 + sl * 2;
        qp[0] = ep[0]; qp[1] = ep[1];
    }

    // diff = sum x^2 - 2 * sum best  (exact expansion of ||x - e||^2)
    if (t == 0) atomicAdd(diffsum, sred[0] - 2.0f * sred[1]);

    // Coalesced EMA scatter: wave w -> rows w*8..w*8+7, lane = d.
    {
        int wid = t >> 6, lane = t & 63;
        #pragma unroll
        for (int jj = 0; jj < 8; ++jj) {
            int lr = wid * 8 + jj;
            int k = fbk[lr];
            atomicAdd(&esum[k * 64 + lane], input[(size_t)(base + lr) * 64 + lane]);
        }
    }
}

// new_cluster_size + its sum + diff finalize (single block).
__global__ __launch_bounds__(512) void k_ncs(const float* __restrict__ cluster_size,
                                             const float* __restrict__ ws,
                                             float* __restrict__ out,
                                             float* __restrict__ wsw) {
    __shared__ float red[512];
    int t = threadIdx.x;
    float ncs = cluster_size[t] * 0.99f + (1.0f - 0.99f) * ws[WS_CNT + t];
    out[OFF_NCS + t] = ncs;
    red[t] = ncs;
    __syncthreads();
    for (int off = 256; off > 0; off >>= 1) {
        if (t < off) red[t] += red[t + off];
        __syncthreads();
    }
    if (t == 0) {
        wsw[WS_NTOT] = red[0];
        out[OFF_DIFF] = ws[WS_DIFF] * (1.0f / 4194304.0f);
    }
}

// new_embed_avg + embed_new.
__global__ __launch_bounds__(512) void k_emb(const float* __restrict__ embed_avg,
                                             const float* __restrict__ ws,
                                             float* __restrict__ out) {
    int d = blockIdx.x;
    int t = threadIdx.x;
    float ncs = out[OFF_NCS + t];
    float ntot = ws[WS_NTOT];
    float csk = (ncs + 1e-5f) / (ntot + 512.0f * 1e-5f) * ntot;
    int idx = d * KC + t;
    float avg = embed_avg[idx] * 0.99f + (1.0f - 0.99f) * ws[WS_ESUM + t * 64 + d];
    out[OFF_NAVG + idx] = avg;
    out[OFF_ENEW + idx] = avg / csk;
}

extern "C" void kernel_launch(void* const* d_in, const int* in_sizes, int n_in,
                              void* d_out, int out_size, void* d_ws, size_t ws_size,
                              hipStream_t stream) {
    const float* input        = (const float*)d_in[0];
    const float* embed        = (const float*)d_in[1];
    const float* cluster_size = (const float*)d_in[2];
    const float* embed_avg    = (const float*)d_in[3];
    float* out = (float*)d_out;
    float* ws  = (float*)d_ws;

    k_prep<<<131, 256, 0, stream>>>(embed, ws);
    k_main<<<2048, 256, 0, stream>>>(input, embed, ws + WS_ET, ws + WS_C, out,
                                     ws + WS_CNT, ws + WS_ESUM, ws + WS_DIFF);
    k_ncs<<<1, 512, 0, stream>>>(cluster_size, ws, out, ws);
    k_emb<<<64, 512, 0, stream>>>(embed_avg, ws, out);
}

// Round 4
// 158.955 us; speedup vs baseline: 10.5789x; 1.0502x over previous
//
#include <hip/hip_runtime.h>

#define KC 512
#define NR 65536

// d_out layout (floats), reference return order:
// quantize_st[4194304], diff[1], embed_ind[65536], embed_new[32768],
// new_cluster_size[512], new_embed_avg[32768]
#define OFF_Q     0
#define OFF_DIFF  4194304
#define OFF_IND   4194305
#define OFF_ENEW  4259841
#define OFF_NCS   4292609
#define OFF_NAVG  4293121

// ws layout (floats)
#define WS_ET    0        // 32768: embed transposed [K][D]
#define WS_C     32768    // 512:   0.5*||e_k||^2
#define WS_CNT   33280    // 512:   one-hot counts
#define WS_ESUM  33792    // 32768: embed_sum transposed [K][D]
#define WS_DIFF  66560    // 1:     sum of squared diff
#define WS_NTOT  66561    // 1:     sum of new_cluster_size

// Prep: transpose embed [D][K] -> Et [K][D], code-norm bias, zero accumulators.
__global__ __launch_bounds__(256) void k_prep(const float* __restrict__ embed,
                                              float* __restrict__ ws) {
    int i = blockIdx.x * 256 + threadIdx.x;
    if (i < 512 + 32768 + 2) ws[WS_CNT + i] = 0.0f;   // counts, esum, diff, ntot
    if (i < 32768) {
        int k = i >> 6, d = i & 63;
        ws[WS_ET + i] = embed[d * KC + k];
    }
    if (i < 512) {
        float s = 0.0f;
        #pragma unroll
        for (int d = 0; d < 64; ++d) { float e = embed[d * KC + i]; s = fmaf(e, e, s); }
        ws[WS_C + i] = 0.5f * s;
    }
}

// Scalar-operand GEMM kernel. Block = 256 threads = 4 waves.
// lane (t&63) -> row base+lane, its x[64] in VGPRs.
// wave (t>>6) -> 128-code chunk; code index is WAVE-UNIFORM -> Et reads
// become s_load through the scalar cache; inner loop is pure v_fma(v,s,v).
__global__ __launch_bounds__(256, 4) void k_main(const float* __restrict__ input,
                                                 const float* __restrict__ Et,   // [512][64]
                                                 const float* __restrict__ c,
                                                 float* __restrict__ out,
                                                 float* __restrict__ counts,
                                                 float* __restrict__ esum,
                                                 float* __restrict__ diffsum) {
    __shared__ float sbest[4][64];
    __shared__ int   sidx[4][64];
    __shared__ int   fbk[64];

    const int t     = threadIdx.x;
    const int lane  = t & 63;
    const int chunk = __builtin_amdgcn_readfirstlane(t >> 6);  // provably uniform
    const int base  = blockIdx.x * 64;
    const int row   = base + lane;

    // Per-lane x row -> 64 VGPRs; also sum of x^2 for the diff expansion.
    float X[64];
    float xs = 0.0f;
    {
        const float4* xp = reinterpret_cast<const float4*>(input + (size_t)row * 64);
        #pragma unroll
        for (int i = 0; i < 16; ++i) {
            float4 v = xp[i];
            X[4*i+0] = v.x; X[4*i+1] = v.y; X[4*i+2] = v.z; X[4*i+3] = v.w;
            xs += v.x*v.x + v.y*v.y + v.z*v.z + v.w*v.w;
        }
    }

    // 128 codes per wave, 4 at a time (4 independent FMA chains, all operands
    // from SGPRs; summation order identical to rounds 2/3).
    float best = -3.0e38f; int bk = 0;
    const int k0 = chunk * 128;
    for (int kk = 0; kk < 128; kk += 4) {
        const int k = k0 + kk;
        const float* __restrict__ e0 = Et + (size_t)(k + 0) * 64;
        const float* __restrict__ e1 = Et + (size_t)(k + 1) * 64;
        const float* __restrict__ e2 = Et + (size_t)(k + 2) * 64;
        const float* __restrict__ e3 = Et + (size_t)(k + 3) * 64;
        float s0 = -c[k + 0], s1 = -c[k + 1], s2 = -c[k + 2], s3 = -c[k + 3];
        #pragma unroll
        for (int d = 0; d < 64; ++d) {
            float xd = X[d];
            s0 = fmaf(xd, e0[d], s0);
            s1 = fmaf(xd, e1[d], s1);
            s2 = fmaf(xd, e2[d], s2);
            s3 = fmaf(xd, e3[d], s3);
        }
        if (s0 > best) { best = s0; bk = k;     }
        if (s1 > best) { best = s1; bk = k + 1; }
        if (s2 > best) { best = s2; bk = k + 2; }
        if (s3 > best) { best = s3; bk = k + 3; }
    }
    sbest[chunk][lane] = best;
    sidx[chunk][lane]  = bk;
    __syncthreads();

    // Combine 4 chunks (ascending chunk = ascending k; strict > = lowest-k tie).
    if (chunk == 0) {
        float b = sbest[0][lane]; int k = sidx[0][lane];
        #pragma unroll
        for (int cc = 1; cc < 4; ++cc) {
            float v = sbest[cc][lane]; int kk2 = sidx[cc][lane];
            if (v > b) { b = v; k = kk2; }
        }
        fbk[lane] = k;
        out[OFF_IND + row] = (float)k;
        atomicAdd(&counts[k], 1.0f);
        // diff partial: ||x-e||^2 = ||x||^2 - 2*best
        float ds = xs - 2.0f * b;
        #pragma unroll
        for (int off = 32; off > 0; off >>= 1) ds += __shfl_down(ds, off);
        if (lane == 0) atomicAdd(diffsum, ds);
    }
    __syncthreads();

    // Epilogue: quantize gather + coalesced EMA scatter. lane = d now.
    {
        #pragma unroll
        for (int j = 0; j < 16; ++j) {
            int r = chunk * 16 + j;
            int k = fbk[r];
            float e = Et[(size_t)k * 64 + lane];
            out[OFF_Q + (size_t)(base + r) * 64 + lane] = e;
            atomicAdd(&esum[k * 64 + lane], input[(size_t)(base + r) * 64 + lane]);
        }
    }
}

// new_cluster_size + its sum + diff finalize (single block).
__global__ __launch_bounds__(512) void k_ncs(const float* __restrict__ cluster_size,
                                             const float* __restrict__ ws,
                                             float* __restrict__ out,
                                             float* __restrict__ wsw) {
    __shared__ float red[512];
    int t = threadIdx.x;
    float ncs = cluster_size[t] * 0.99f + (1.0f - 0.99f) * ws[WS_CNT + t];
    out[OFF_NCS + t] = ncs;
    red[t] = ncs;
    __syncthreads();
    for (int off = 256; off > 0; off >>= 1) {
        if (t < off) red[t] += red[t + off];
        __syncthreads();
    }
    if (t == 0) {
        wsw[WS_NTOT] = red[0];
        out[OFF_DIFF] = ws[WS_DIFF] * (1.0f / 4194304.0f);
    }
}

// new_embed_avg + embed_new.
__global__ __launch_bounds__(512) void k_emb(const float* __restrict__ embed_avg,
                                             const float* __restrict__ ws,
                                             float* __restrict__ out) {
    int d = blockIdx.x;
    int t = threadIdx.x;
    float ncs = out[OFF_NCS + t];
    float ntot = ws[WS_NTOT];
    float csk = (ncs + 1e-5f) / (ntot + 512.0f * 1e-5f) * ntot;
    int idx = d * KC + t;
    float avg = embed_avg[idx] * 0.99f + (1.0f - 0.99f) * ws[WS_ESUM + t * 64 + d];
    out[OFF_NAVG + idx] = avg;
    out[OFF_ENEW + idx] = avg / csk;
}

extern "C" void kernel_launch(void* const* d_in, const int* in_sizes, int n_in,
                              void* d_out, int out_size, void* d_ws, size_t ws_size,
                              hipStream_t stream) {
    const float* input        = (const float*)d_in[0];
    const float* embed        = (const float*)d_in[1];
    const float* cluster_size = (const float*)d_in[2];
    const float* embed_avg    = (const float*)d_in[3];
    float* out = (float*)d_out;
    float* ws  = (float*)d_ws;

    k_prep<<<131, 256, 0, stream>>>(embed, ws);
    k_main<<<1024, 256, 0, stream>>>(input, ws + WS_ET, ws + WS_C, out,
                                     ws + WS_CNT, ws + WS_ESUM, ws + WS_DIFF);
    k_ncs<<<1, 512, 0, stream>>>(cluster_size, ws, out, ws);
    k_emb<<<64, 512, 0, stream>>>(embed_avg, ws, out);
}